// Round 7
// baseline (128.933 us; speedup 1.0000x reference)
//
#include <hip/hip_runtime.h>
#include <hip/hip_bf16.h>
#include <cstddef>
#include <cstdint>

#define NE 65536
#define ND 256
#define NP 8
#define RBLK 256             // routing/scatter blocks
#define EPB (NE / RBLK)      // 256 edges per routing block
#define MAXT 1032            // max tiles: 1024 + 7

typedef short bf16x8 __attribute__((ext_vector_type(8)));
typedef float f32x4  __attribute__((ext_vector_type(4)));

__device__ __forceinline__ unsigned short f2bf(float f) {
  unsigned int u = __float_as_uint(f);
  u += 0x7FFFu + ((u >> 16) & 1u);   // round-to-nearest-even
  return (unsigned short)(u >> 16);
}

// Per-block idx-dtype sniff (sample 256 odd words from the first 32768 words;
// int64 => all zero; int32 => nonzero w.p. 1-(1/8)^256).
__device__ __forceinline__ int sniff_is32(const void* idxraw, int* lflag) {
  int tid = threadIdx.x;
  if (tid == 0) *lflag = 0;
  __syncthreads();
  const unsigned int* w = (const unsigned int*)idxraw;
  unsigned int val = w[((blockIdx.x & 63) * 256 + tid) * 2 + 1];
  if (__any(val != 0) && (tid & 63) == 0) atomicOr(lflag, 1);
  __syncthreads();
  return *lflag;
}

__device__ __forceinline__ int load_idx(const void* idxraw, int is32, int e) {
  return is32 ? ((const int*)idxraw)[e] : (int)((const long long*)idxraw)[e];
}

// ---- phase 1: per-block LDS histogram ----
__global__ __launch_bounds__(256) void k_hist(const void* __restrict__ idxraw,
                                              int* __restrict__ counts) {
  __shared__ int h[NP];
  __shared__ int lflag;
  int tid = threadIdx.x;
  int is32 = sniff_is32(idxraw, &lflag);
  if (tid < NP) h[tid] = 0;
  __syncthreads();
  int p = load_idx(idxraw, is32, blockIdx.x * EPB + tid);
  atomicAdd(&h[p], 1);
  __syncthreads();
  if (tid < NP) counts[blockIdx.x * NP + tid] = h[tid];
}

// ---- phase 2: totals, CSR offsets, tile prefix, per-block bases ----
// hdr[0..8]=edge prefix off[9]; hdr[9..17]=tile prefix tb[9]
__global__ __launch_bounds__(64) void k_scan(const int* __restrict__ counts,
                                             int* __restrict__ hdr,
                                             int* __restrict__ bases) {
  __shared__ int cnt[NP];
  __shared__ int off[NP + 1];
  int q = threadIdx.x;
  if (q < NP) {
    int s = 0;
    for (int b = 0; b < RBLK; ++b) s += counts[b * NP + q];
    cnt[q] = s;
  }
  __syncthreads();
  if (q == 0) {
    int o = 0, tt = 0;
    for (int p = 0; p < NP; ++p) {
      off[p] = o; hdr[p] = o; hdr[9 + p] = tt;
      o += cnt[p];
      tt += (cnt[p] + 63) >> 6;
    }
    off[NP] = o; hdr[NP] = o; hdr[9 + NP] = tt;
  }
  __syncthreads();
  if (q < NP) {
    int run = off[q];
    for (int b = 0; b < RBLK; ++b) {
      bases[b * NP + q] = run;
      run += counts[b * NP + q];
    }
  }
}

// ---- phase 3 (FAST): scatter + MOVE: stream z rows in natural order,
// convert to bf16, write to expert-sorted slots. zsrcP in A-frag tile layout,
// zdstP row-major + XOR swizzle. Reads are fully sequential; scattered
// writes are latency-tolerant and land in L2/L3.
__global__ __launch_bounds__(256) void k_scatter_mv(const void* __restrict__ idxraw,
                                                    const float* __restrict__ zsrc,
                                                    const float* __restrict__ zdst,
                                                    const int* __restrict__ hdr,
                                                    const int* __restrict__ bases,
                                                    int* __restrict__ perm,
                                                    unsigned short* __restrict__ zsrcP,
                                                    unsigned short* __restrict__ zdstP) {
  __shared__ int cur[NP];
  __shared__ int soff[NP], stb[NP];
  __shared__ int lflag;
  int tid = threadIdx.x;
  int is32 = sniff_is32(idxraw, &lflag);
  if (tid < NP) {
    cur[tid] = bases[blockIdx.x * NP + tid];
    soff[tid] = hdr[tid];
    stb[tid] = hdr[9 + tid];
  }
  __syncthreads();
  int w = tid >> 6, l = tid & 63;
  int e = blockIdx.x * EPB + w * 64 + l;       // this lane's edge (natural order)
  int p = load_idx(idxraw, is32, e);
  int slot = atomicAdd(&cur[p], 1);            // LDS atomic, unique CSR slot
  perm[slot] = e;
  int local = slot - soff[p];
  int tile = stb[p] + (local >> 6);
  int row = local & 63;
  int c0 = l * 4;
  // A-frag position pieces that depend only on this lane's column range:
#pragma unroll 8
  for (int i = 0; i < 64; ++i) {
    int ei = __shfl(e, i, 64);
    int ti = __shfl(tile, i, 64);
    int ri = __shfl(row, i, 64);
    float4 fs = *(const float4*)(zsrc + (size_t)ei * ND + c0);   // sequential 1KB/wave
    float4 fd = *(const float4*)(zdst + (size_t)ei * ND + c0);
    union { unsigned long long u; unsigned short h[4]; } us, ud;
    us.h[0] = f2bf(fs.x); us.h[1] = f2bf(fs.y); us.h[2] = f2bf(fs.z); us.h[3] = f2bf(fs.w);
    ud.h[0] = f2bf(fd.x); ud.h[1] = f2bf(fd.y); ud.h[2] = f2bf(fd.z); ud.h[3] = f2bf(fd.w);
    int fslot = ((c0 >> 5) * 4 + (ri >> 4)) * 64 + ((c0 & 31) >> 3) * 16 + (ri & 15);
    *(unsigned long long*)((char*)zsrcP + (size_t)ti * 32768 + fslot * 16 + (c0 & 7) * 2) = us.u;
    *(unsigned long long*)((char*)zdstP + (size_t)ti * 32768 + ri * 512 + ((l * 8) ^ ((ri & 7) << 4))) = ud.u;
  }
}

// ---- phase 3 (FALLBACK, small ws): plain CSR scatter ----
__global__ __launch_bounds__(256) void k_scatter(const void* __restrict__ idxraw,
                                                 const int* __restrict__ bases,
                                                 int* __restrict__ perm) {
  __shared__ int cur[NP];
  __shared__ int lflag;
  int tid = threadIdx.x;
  int is32 = sniff_is32(idxraw, &lflag);
  if (tid < NP) cur[tid] = bases[blockIdx.x * NP + tid];
  __syncthreads();
  int e = blockIdx.x * EPB + tid;
  int p = load_idx(idxraw, is32, e);
  int slot = atomicAdd(&cur[p], 1);
  perm[slot] = e;
}

// ---- prep: W_bil -> B-frag bf16 layout; v_p = b_lr[p] @ W_bil (fp32) ----
__global__ __launch_bounds__(256) void k_prep(const float* __restrict__ Wbil,
                                              const float* __restrict__ blr,
                                              unsigned short* __restrict__ WbT,
                                              float* __restrict__ v) {
  int b = blockIdx.x, t = threadIdx.x;
  if (b < 32) {
    int s = b * 256 + t;
    int kt = s >> 10, c = (s >> 6) & 15, l = s & 63;
    int col = c * 16 + (l & 15);
    int k0 = kt * 32 + (l >> 4) * 8;
    union { uint4 u; unsigned short h[8]; } uu;
#pragma unroll
    for (int j = 0; j < 8; ++j)
      uu.h[j] = f2bf(Wbil[(k0 + j) * ND + col]);
    *(uint4*)(WbT + (size_t)s * 8) = uu.u;
  } else {
    int p = b - 32;
    float s = 0.f;
    for (int k = 0; k < ND; ++k)
      s = fmaf(blr[p * ND + k], Wbil[k * ND + t], s);
    v[p * ND + t] = s;
  }
}

// ---- C_p = W_lr[p]^T @ W_bil  (bf16 MFMA), written in B-frag layout ----
__global__ __launch_bounds__(256) void k_cpre(const float* __restrict__ Wlr,
                                              const unsigned short* __restrict__ WbT,
                                              unsigned short* __restrict__ Cst) {
  __shared__ unsigned short aF[2048 * 8];
  int blk = blockIdx.x;
  int p = blk >> 2;
  int i0 = (blk & 3) * 64;
  int tid = threadIdx.x;
  const float* Wp = Wlr + (size_t)p * ND * ND;
#pragma unroll
  for (int it = 0; it < 8; ++it) {
    int s = tid + it * 256;
    int kt = s >> 8, r = (s >> 6) & 3, l = s & 63;
    int i = r * 16 + (l & 15);
    int k0 = kt * 32 + (l >> 4) * 8;
    union { uint4 u; unsigned short h[8]; } uu;
#pragma unroll
    for (int j = 0; j < 8; ++j)
      uu.h[j] = f2bf(Wp[(size_t)(k0 + j) * ND + i0 + i]);
    *(uint4*)(aF + (size_t)s * 8) = uu.u;
  }
  __syncthreads();
  int w = tid >> 6, l = tid & 63;
  f32x4 zero = {0.f, 0.f, 0.f, 0.f};
  f32x4 acc[16];
#pragma unroll
  for (int c = 0; c < 16; ++c) acc[c] = zero;
  for (int kt = 0; kt < 8; ++kt) {
    bf16x8 a = *(const bf16x8*)(aF + (size_t)((kt * 4 + w) * 64 + l) * 8);
#pragma unroll
    for (int c = 0; c < 16; ++c) {
      bf16x8 bb = *(const bf16x8*)(WbT + (size_t)((kt * 16 + c) * 64 + l) * 8);
      acc[c] = __builtin_amdgcn_mfma_f32_16x16x32_bf16(a, bb, acc[c], 0, 0, 0);
    }
  }
  unsigned short* Cp = Cst + (size_t)p * ND * ND;
#pragma unroll
  for (int c = 0; c < 16; ++c) {
#pragma unroll
    for (int q = 0; q < 4; ++q) {
      int i = i0 + w * 16 + ((l >> 4) * 4) + q;
      int j = c * 16 + (l & 15);
      int pos = ((i >> 5) * 16 + (j >> 4)) * 512 + (((i >> 3) & 3) * 16 + (j & 15)) * 8 + (i & 7);
      Cp[pos] = f2bf(acc[c][q]);
    }
  }
}

// ---- main (FAST): tile data already gathered/converted/layout'd; staging is
// a verbatim sequential 64KB copy (tile index == blockIdx).
__global__ __launch_bounds__(256, 2) void k_main_f(const unsigned short* __restrict__ zsrcP,
                                                   const unsigned short* __restrict__ zdstP,
                                                   const int* __restrict__ perm,
                                                   const int* __restrict__ hdr,
                                                   const unsigned short* __restrict__ Cst,
                                                   const float* __restrict__ v,
                                                   const float* __restrict__ bbil,
                                                   float* __restrict__ out) {
  __shared__ unsigned short aF[2048 * 8];      // 32 KiB A-frag tile
  __shared__ unsigned short zL[64 * 256];      // 32 KiB zdst tile (swizzled rows)
  __shared__ int eids[64];
  __shared__ int shdr[18];
  __shared__ float red[4][64];
  int tid = threadIdx.x;
  if (tid < 18) shdr[tid] = hdr[tid];
  __syncthreads();
  int bid = blockIdx.x;
  if (bid >= shdr[9 + NP]) return;
  int p = 0;
  while (p < NP - 1 && bid >= shdr[9 + p + 1]) ++p;
  int t = bid - shdr[9 + p];
  int cnt = shdr[p + 1] - shdr[p];
  int ebase = shdr[p] + t * 64;
  int nrow = cnt - t * 64; if (nrow > 64) nrow = 64;
  if (tid < 64) eids[tid] = perm[ebase + (tid < nrow ? tid : nrow - 1)];
  const uint4* gA = (const uint4*)((const char*)zsrcP + (size_t)bid * 32768);
  const uint4* gZ = (const uint4*)((const char*)zdstP + (size_t)bid * 32768);
  uint4 ra[8], rz[8];
#pragma unroll
  for (int i = 0; i < 8; ++i) ra[i] = gA[i * 256 + tid];
#pragma unroll
  for (int i = 0; i < 8; ++i) rz[i] = gZ[i * 256 + tid];
#pragma unroll
  for (int i = 0; i < 8; ++i) ((uint4*)aF)[i * 256 + tid] = ra[i];
#pragma unroll
  for (int i = 0; i < 8; ++i) ((uint4*)zL)[i * 256 + tid] = rz[i];
  __syncthreads();

  int w = tid >> 6, l = tid & 63;
  const unsigned short* Cp = Cst + (size_t)p * ND * ND;
  f32x4 zero = {0.f, 0.f, 0.f, 0.f};
  f32x4 acc[4][4];
#pragma unroll
  for (int r = 0; r < 4; ++r)
#pragma unroll
    for (int c = 0; c < 4; ++c) acc[r][c] = zero;
#pragma unroll
  for (int kt = 0; kt < 8; ++kt) {
    bf16x8 a[4];
#pragma unroll
    for (int r = 0; r < 4; ++r)
      a[r] = *(const bf16x8*)(aF + (size_t)((kt * 4 + r) * 64 + l) * 8);
#pragma unroll
    for (int cl = 0; cl < 4; ++cl) {
      bf16x8 bb = *(const bf16x8*)(Cp + (size_t)((kt * 16 + w * 4 + cl) * 64 + l) * 8);
#pragma unroll
      for (int r = 0; r < 4; ++r)
        acc[r][cl] = __builtin_amdgcn_mfma_f32_16x16x32_bf16(a[r], bb, acc[r][cl], 0, 0, 0);
    }
  }
  float vloc[4];
#pragma unroll
  for (int cl = 0; cl < 4; ++cl)
    vloc[cl] = v[p * ND + (w * 4 + cl) * 16 + (l & 15)];
#pragma unroll
  for (int r = 0; r < 4; ++r) {
#pragma unroll
    for (int q = 0; q < 4; ++q) {
      int row = r * 16 + ((l >> 4) * 4) + q;
      unsigned int swz = (unsigned int)((row & 7) << 4);
      float sv = 0.f;
#pragma unroll
      for (int cl = 0; cl < 4; ++cl) {
        int col = (w * 4 + cl) * 16 + (l & 15);
        unsigned int zb = (unsigned int)(row * 512) + (((unsigned int)(col * 2)) ^ swz);
        unsigned short hz = *(const unsigned short*)((const char*)zL + zb);
        float zv = __uint_as_float(((unsigned int)hz) << 16);
        sv = fmaf(acc[r][cl][q] + vloc[cl], zv, sv);
      }
      sv += __shfl_xor(sv, 1, 64);
      sv += __shfl_xor(sv, 2, 64);
      sv += __shfl_xor(sv, 4, 64);
      sv += __shfl_xor(sv, 8, 64);
      if ((l & 15) == 0) red[w][row] = sv;
    }
  }
  __syncthreads();
  if (tid < 64 && tid < nrow) {
    float sc = red[0][tid] + red[1][tid] + red[2][tid] + red[3][tid] + bbil[0];
    out[eids[tid]] = sc;
  }
}

// ---- main (FALLBACK): R6 gather version ----
__global__ __launch_bounds__(256, 2) void k_main_g(const float* __restrict__ zsrc,
                                                   const float* __restrict__ zdst,
                                                   const int* __restrict__ perm,
                                                   const int* __restrict__ hdr,
                                                   const unsigned short* __restrict__ Cst,
                                                   const float* __restrict__ v,
                                                   const float* __restrict__ bbil,
                                                   float* __restrict__ out) {
  __shared__ unsigned short aF[2048 * 8];
  __shared__ unsigned short zL[64 * 256];
  __shared__ int eids[64];
  __shared__ int shdr[18];
  __shared__ float red[4][64];
  int tid = threadIdx.x;
  if (tid < 18) shdr[tid] = hdr[tid];
  __syncthreads();
  int bid = blockIdx.x;
  if (bid >= shdr[9 + NP]) return;
  int p = 0;
  while (p < NP - 1 && bid >= shdr[9 + p + 1]) ++p;
  int t = bid - shdr[9 + p];
  int cnt = shdr[p + 1] - shdr[p];
  int ebase = shdr[p] + t * 64;
  int nrow = cnt - t * 64; if (nrow > 64) nrow = 64;
  if (tid < 64) eids[tid] = perm[ebase + (tid < nrow ? tid : nrow - 1)];
  __syncthreads();
  int w = tid >> 6, l = tid & 63;
#pragma unroll
  for (int i = 0; i < 16; ++i) {
    int row = w * 16 + i;
    int e = eids[row];
    f32x4 fs = ((const f32x4*)(zsrc + (size_t)e * ND))[l];
    f32x4 fd = ((const f32x4*)(zdst + (size_t)e * ND))[l];
    union { ushort4 u; unsigned short h[4]; } us, ud;
#pragma unroll
    for (int j = 0; j < 4; ++j) { us.h[j] = f2bf(fs[j]); ud.h[j] = f2bf(fd[j]); }
    *(ushort4*)((char*)zL + row * 512 + ((l * 8) ^ ((row & 7) << 4))) = ud.u;
    int slot = ((l >> 3) * 4 + w) * 64 + ((l & 7) >> 1) * 16 + i;
    *(ushort4*)((char*)aF + slot * 16 + (l & 1) * 8) = us.u;
  }
  __syncthreads();
  const unsigned short* Cp = Cst + (size_t)p * ND * ND;
  f32x4 zero = {0.f, 0.f, 0.f, 0.f};
  f32x4 acc[4][4];
#pragma unroll
  for (int r = 0; r < 4; ++r)
#pragma unroll
    for (int c = 0; c < 4; ++c) acc[r][c] = zero;
#pragma unroll
  for (int kt = 0; kt < 8; ++kt) {
    bf16x8 a[4];
#pragma unroll
    for (int r = 0; r < 4; ++r)
      a[r] = *(const bf16x8*)(aF + (size_t)((kt * 4 + r) * 64 + l) * 8);
#pragma unroll
    for (int cl = 0; cl < 4; ++cl) {
      bf16x8 bb = *(const bf16x8*)(Cp + (size_t)((kt * 16 + w * 4 + cl) * 64 + l) * 8);
#pragma unroll
      for (int r = 0; r < 4; ++r)
        acc[r][cl] = __builtin_amdgcn_mfma_f32_16x16x32_bf16(a[r], bb, acc[r][cl], 0, 0, 0);
    }
  }
  float vloc[4];
#pragma unroll
  for (int cl = 0; cl < 4; ++cl)
    vloc[cl] = v[p * ND + (w * 4 + cl) * 16 + (l & 15)];
#pragma unroll
  for (int r = 0; r < 4; ++r) {
#pragma unroll
    for (int q = 0; q < 4; ++q) {
      int row = r * 16 + ((l >> 4) * 4) + q;
      unsigned int swz = (unsigned int)((row & 7) << 4);
      float sv = 0.f;
#pragma unroll
      for (int cl = 0; cl < 4; ++cl) {
        int col = (w * 4 + cl) * 16 + (l & 15);
        unsigned int zb = (unsigned int)(row * 512) + (((unsigned int)(col * 2)) ^ swz);
        unsigned short hz = *(const unsigned short*)((const char*)zL + zb);
        float zv = __uint_as_float(((unsigned int)hz) << 16);
        sv = fmaf(acc[r][cl][q] + vloc[cl], zv, sv);
      }
      sv += __shfl_xor(sv, 1, 64);
      sv += __shfl_xor(sv, 2, 64);
      sv += __shfl_xor(sv, 4, 64);
      sv += __shfl_xor(sv, 8, 64);
      if ((l & 15) == 0) red[w][row] = sv;
    }
  }
  __syncthreads();
  if (tid < 64 && tid < nrow) {
    float sc = red[0][tid] + red[1][tid] + red[2][tid] + red[3][tid] + bbil[0];
    out[eids[tid]] = sc;
  }
}

extern "C" void kernel_launch(void* const* d_in, const int* in_sizes, int n_in,
                              void* d_out, int out_size, void* d_ws, size_t ws_size,
                              hipStream_t stream) {
  // setup_inputs() dict order: z_src, z_dst, W_lr, b_lr, W_bil, b_bil, lr_pair_idx
  const float* zsrc = (const float*)d_in[0];
  const float* zdst = (const float*)d_in[1];
  const float* Wlr  = (const float*)d_in[2];
  const float* blr  = (const float*)d_in[3];
  const float* Wbil = (const float*)d_in[4];
  const float* bbil = (const float*)d_in[5];
  const void*  idx  = (const void*)d_in[6];
  float* out = (float*)d_out;

  char* ws = (char*)d_ws;
  int* hdr    = (int*)ws;                                  // 72 B
  int* counts = (int*)(ws + 4096);                         // 8 KiB (256*8*4)
  int* bases  = (int*)(ws + 12288);                        // 8 KiB
  int* perm   = (int*)(ws + 20480);                        // 256 KiB
  unsigned short* WbT = (unsigned short*)(ws + 282624);    // 128 KiB
  float* v            = (float*)(ws + 413696);             // 8 KiB
  unsigned short* Cst = (unsigned short*)(ws + 421888);    // 1 MiB -> ends 1470464
  size_t zoff = 2097152;
  unsigned short* zsrcP = (unsigned short*)(ws + zoff);                      // 33816576 B
  unsigned short* zdstP = (unsigned short*)(ws + zoff + (size_t)MAXT * 32768);
  size_t need = zoff + 2ull * (size_t)MAXT * 32768;        // ~69.7 MB

  k_prep<<<40, 256, 0, stream>>>(Wbil, blr, WbT, v);
  k_hist<<<RBLK, 256, 0, stream>>>(idx, counts);
  k_scan<<<1, 64, 0, stream>>>(counts, hdr, bases);
  k_cpre<<<32, 256, 0, stream>>>(Wlr, WbT, Cst);
  if (ws_size >= need) {
    k_scatter_mv<<<RBLK, 256, 0, stream>>>(idx, zsrc, zdst, hdr, bases, perm, zsrcP, zdstP);
    k_main_f<<<MAXT, 256, 0, stream>>>(zsrcP, zdstP, perm, hdr, Cst, v, bbil, out);
  } else {
    k_scatter<<<RBLK, 256, 0, stream>>>(idx, bases, perm);
    k_main_g<<<MAXT, 256, 0, stream>>>(zsrc, zdst, perm, hdr, Cst, v, bbil, out);
  }
}

// Round 8
// 98.943 us; speedup vs baseline: 1.3031x; 1.3031x over previous
//
#include <hip/hip_runtime.h>
#include <hip/hip_bf16.h>
#include <cstddef>

#define NE 65536
#define ND 256
#define NP 8
#define EB 64                // edges per fused block (local sort window)
#define NB (NE / EB)         // 1024 blocks

typedef short bf16x8 __attribute__((ext_vector_type(8)));
typedef float f32x4  __attribute__((ext_vector_type(4)));

__device__ __forceinline__ unsigned short f2bf(float f) {
  unsigned int u = __float_as_uint(f);
  u += 0x7FFFu + ((u >> 16) & 1u);   // round-to-nearest-even
  return (unsigned short)(u >> 16);
}
__device__ __forceinline__ float bf2f(unsigned short h) {
  return __uint_as_float(((unsigned int)h) << 16);
}
__device__ __forceinline__ int load_idx(const void* idxraw, int is32, int e) {
  return is32 ? ((const int*)idxraw)[e] : (int)((const long long*)idxraw)[e];
}

// ---- prep: W_bil -> B-frag bf16 layout; v_p = b_lr[p] @ W_bil (fp32) ----
__global__ __launch_bounds__(256) void k_prep(const float* __restrict__ Wbil,
                                              const float* __restrict__ blr,
                                              unsigned short* __restrict__ WbT,
                                              float* __restrict__ v) {
  int b = blockIdx.x, t = threadIdx.x;
  if (b < 32) {
    int s = b * 256 + t;
    int kt = s >> 10, c = (s >> 6) & 15, l = s & 63;
    int col = c * 16 + (l & 15);
    int k0 = kt * 32 + (l >> 4) * 8;
    union { uint4 u; unsigned short h[8]; } uu;
#pragma unroll
    for (int j = 0; j < 8; ++j)
      uu.h[j] = f2bf(Wbil[(k0 + j) * ND + col]);
    *(uint4*)(WbT + (size_t)s * 8) = uu.u;
  } else {
    int p = b - 32;
    float s = 0.f;
    for (int k = 0; k < ND; ++k)
      s = fmaf(blr[p * ND + k], Wbil[k * ND + t], s);
    v[p * ND + t] = s;
  }
}

// ---- C_p = W_lr[p]^T @ W_bil  (bf16 MFMA), written in B-frag layout ----
__global__ __launch_bounds__(256) void k_cpre(const float* __restrict__ Wlr,
                                              const unsigned short* __restrict__ WbT,
                                              unsigned short* __restrict__ Cst) {
  __shared__ unsigned short aF[2048 * 8];
  int blk = blockIdx.x;
  int p = blk >> 2;
  int i0 = (blk & 3) * 64;
  int tid = threadIdx.x;
  const float* Wp = Wlr + (size_t)p * ND * ND;
#pragma unroll
  for (int it = 0; it < 8; ++it) {
    int s = tid + it * 256;
    int kt = s >> 8, r = (s >> 6) & 3, l = s & 63;
    int i = r * 16 + (l & 15);
    int k0 = kt * 32 + (l >> 4) * 8;
    union { uint4 u; unsigned short h[8]; } uu;
#pragma unroll
    for (int j = 0; j < 8; ++j)
      uu.h[j] = f2bf(Wp[(size_t)(k0 + j) * ND + i0 + i]);
    *(uint4*)(aF + (size_t)s * 8) = uu.u;
  }
  __syncthreads();
  int w = tid >> 6, l = tid & 63;
  f32x4 zero = {0.f, 0.f, 0.f, 0.f};
  f32x4 acc[16];
#pragma unroll
  for (int c = 0; c < 16; ++c) acc[c] = zero;
  for (int kt = 0; kt < 8; ++kt) {
    bf16x8 a = *(const bf16x8*)(aF + (size_t)((kt * 4 + w) * 64 + l) * 8);
#pragma unroll
    for (int c = 0; c < 16; ++c) {
      bf16x8 bb = *(const bf16x8*)(WbT + (size_t)((kt * 16 + c) * 64 + l) * 8);
      acc[c] = __builtin_amdgcn_mfma_f32_16x16x32_bf16(a, bb, acc[c], 0, 0, 0);
    }
  }
  unsigned short* Cp = Cst + (size_t)p * ND * ND;
#pragma unroll
  for (int c = 0; c < 16; ++c) {
#pragma unroll
    for (int q = 0; q < 4; ++q) {
      int i = i0 + w * 16 + ((l >> 4) * 4) + q;
      int j = c * 16 + (l & 15);
      int pos = ((i >> 5) * 16 + (j >> 4)) * 512 + (((i >> 3) & 3) * 16 + (j & 15)) * 8 + (i & 7);
      Cp[pos] = f2bf(acc[c][q]);
    }
  }
}

// ---- fused: 64 consecutive edges per block, LOCAL expert sort in LDS,
// per-expert 16-row strip MFMAs at arbitrary offsets, fused bilinear epilogue.
// Reads of z_src/z_dst are purely sequential (no global permutation at all).
__global__ __launch_bounds__(512, 4) void k_fused(const float* __restrict__ zsrc,
                                                  const float* __restrict__ zdst,
                                                  const void* __restrict__ idxraw,
                                                  const unsigned short* __restrict__ Cst,
                                                  const float* __restrict__ v,
                                                  const float* __restrict__ bbil,
                                                  float* __restrict__ out) {
  __shared__ unsigned short aF[16384];   // 32 KiB: 64 rows x 256 k, frag+XOR layout
  __shared__ unsigned short zL[16384];   // 32 KiB: 64 rows x 256, row-major+XOR
  __shared__ float red[8][EB];           // 2 KiB
  __shared__ int h[NP], loff[NP + 1], cur[NP], srt[EB], lsrc[EB];
  __shared__ int stripP[12], stripR0[12], stripEnd[12], nstr;
  __shared__ int lflag;
  int tid = threadIdx.x;
  if (tid == 0) lflag = 0;
  if (tid < NP) { h[tid] = 0; cur[tid] = 0; }
  __syncthreads();
  {  // idx dtype sniff: odd 32-bit words all-zero <=> int64 (values < 8)
    const unsigned int* wd = (const unsigned int*)idxraw;
    unsigned int val = wd[((blockIdx.x & 63) * 512 + tid) * 2 + 1];
    if (__any(val != 0) && (tid & 63) == 0) atomicOr(&lflag, 1);
  }
  __syncthreads();
  int is32 = lflag;
  int base = blockIdx.x * EB;
  int myp = 0;
  if (tid < EB) {
    myp = load_idx(idxraw, is32, base + tid);
    atomicAdd(&h[myp], 1);
  }
  __syncthreads();
  if (tid == 0) {   // prefix + strip table (strips never cross experts)
    int o = 0, ns = 0;
    for (int p = 0; p < NP; ++p) {
      loff[p] = o;
      int c = h[p];
      for (int r0 = 0; r0 < c; r0 += 16) {
        stripP[ns] = p;
        stripR0[ns] = o + r0;
        stripEnd[ns] = o + (c < r0 + 16 ? c : r0 + 16);
        ++ns;
      }
      o += c;
    }
    loff[NP] = o;
    nstr = ns;
  }
  __syncthreads();
  if (tid < EB) {
    int slot = loff[myp] + atomicAdd(&cur[myp], 1);
    srt[tid] = slot;          // natural row -> sorted row
    lsrc[slot] = tid;         // sorted row -> natural row
  }
  __syncthreads();

  int w = tid >> 6, l = tid & 63;
  // ---- staging: sequential reads, locally-permuted LDS writes ----
#pragma unroll
  for (int i = 0; i < 8; ++i) {
    int rnat = w * 8 + i;
    int e = base + rnat;
    int dr = srt[rnat];
    float4 fs = *(const float4*)(zsrc + (size_t)e * ND + l * 4);
    float4 fd = *(const float4*)(zdst + (size_t)e * ND + l * 4);
    union { ushort4 u; unsigned short hh[4]; } us, ud;
    us.hh[0] = f2bf(fs.x); us.hh[1] = f2bf(fs.y); us.hh[2] = f2bf(fs.z); us.hh[3] = f2bf(fs.w);
    ud.hh[0] = f2bf(fd.x); ud.hh[1] = f2bf(fd.y); ud.hh[2] = f2bf(fd.z); ud.hh[3] = f2bf(fd.w);
    // zdst row-major + XOR swizzle (same mapping as R6, verified)
    *(ushort4*)((char*)zL + dr * 512 + ((l * 8) ^ ((dr & 7) << 4))) = ud.u;
    // A-frag: cols c0=4l..4l+3 -> kt=l>>3, pos=(l&7)>>1, par=l&1
    int kt = l >> 3, pos = (l & 7) >> 1, par = l & 1;
    unsigned byte = (unsigned)(((kt * 4 + (dr >> 4)) << 10) | (pos << 8) | ((dr & 15) << 4) | (par << 3));
    byte ^= (unsigned)(((kt & 3) << 5) ^ ((pos & 1) << 4));
    *(ushort4*)((char*)aF + byte) = us.u;
  }
  __syncthreads();

  // ---- per-expert strip GEMM + fused epilogue; wave w covers 32 cols ----
  f32x4 zero = {0.f, 0.f, 0.f, 0.f};
  int ns = nstr;
  int s0 = 0;
  while (s0 < ns) {
    int p = stripP[s0];
    int s1 = s0;
    while (s1 < ns && stripP[s1] == p) ++s1;
    bf16x8 bfr[2][8];
    const unsigned short* Cp = Cst + (size_t)p * ND * ND;
#pragma unroll
    for (int cl = 0; cl < 2; ++cl)
#pragma unroll
      for (int kt = 0; kt < 8; ++kt)
        bfr[cl][kt] = *(const bf16x8*)(Cp + (size_t)((kt * 16 + (w * 2 + cl)) * 64 + l) * 8);
    float vloc[2];
#pragma unroll
    for (int cl = 0; cl < 2; ++cl)
      vloc[cl] = v[p * ND + (w * 2 + cl) * 16 + (l & 15)];
    for (int s = s0; s < s1; ++s) {
      int r0 = stripR0[s], rend = stripEnd[s];
      int rowr = r0 + (l & 15); if (rowr > 63) rowr = 63;   // spill rows: computed, discarded
      int pos = l >> 4;
      f32x4 acc0 = zero, acc1 = zero;
#pragma unroll
      for (int kt = 0; kt < 8; ++kt) {
        unsigned byte = (unsigned)(((kt * 4 + (rowr >> 4)) << 10) | (pos << 8) | ((rowr & 15) << 4));
        byte ^= (unsigned)(((kt & 3) << 5) ^ ((pos & 1) << 4));
        bf16x8 a = *(const bf16x8*)((const char*)aF + byte);
        acc0 = __builtin_amdgcn_mfma_f32_16x16x32_bf16(a, bfr[0][kt], acc0, 0, 0, 0);
        acc1 = __builtin_amdgcn_mfma_f32_16x16x32_bf16(a, bfr[1][kt], acc1, 0, 0, 0);
      }
      // epilogue: row = r0 + (l>>4)*4 + q (D-layout), dot 32 cols with zL
#pragma unroll
      for (int q = 0; q < 4; ++q) {
        int row = r0 + (l >> 4) * 4 + q;
        int rc = row > 63 ? 63 : row;
        unsigned swz = (unsigned)((rc & 7) << 4);
        float sv = 0.f;
        {
          int col = (w * 2 + 0) * 16 + (l & 15);
          unsigned zb = (unsigned)(rc * 512) + (((unsigned)(col * 2)) ^ swz);
          sv = fmaf(acc0[q] + vloc[0], bf2f(*(const unsigned short*)((const char*)zL + zb)), sv);
        }
        {
          int col = (w * 2 + 1) * 16 + (l & 15);
          unsigned zb = (unsigned)(rc * 512) + (((unsigned)(col * 2)) ^ swz);
          sv = fmaf(acc1[q] + vloc[1], bf2f(*(const unsigned short*)((const char*)zL + zb)), sv);
        }
        sv += __shfl_xor(sv, 1, 64);
        sv += __shfl_xor(sv, 2, 64);
        sv += __shfl_xor(sv, 4, 64);
        sv += __shfl_xor(sv, 8, 64);
        if ((l & 15) == 0 && row < rend) red[w][row] = sv;
      }
    }
    s0 = s1;
  }
  __syncthreads();
  if (tid < EB) {
    float sc = bbil[0];
#pragma unroll
    for (int ww = 0; ww < 8; ++ww) sc += red[ww][tid];
    out[base + lsrc[tid]] = sc;
  }
}

extern "C" void kernel_launch(void* const* d_in, const int* in_sizes, int n_in,
                              void* d_out, int out_size, void* d_ws, size_t ws_size,
                              hipStream_t stream) {
  // setup_inputs() dict order: z_src, z_dst, W_lr, b_lr, W_bil, b_bil, lr_pair_idx
  const float* zsrc = (const float*)d_in[0];
  const float* zdst = (const float*)d_in[1];
  const float* Wlr  = (const float*)d_in[2];
  const float* blr  = (const float*)d_in[3];
  const float* Wbil = (const float*)d_in[4];
  const float* bbil = (const float*)d_in[5];
  const void*  idx  = (const void*)d_in[6];
  float* out = (float*)d_out;

  char* ws = (char*)d_ws;
  unsigned short* WbT = (unsigned short*)(ws + 4096);              // 128 KiB
  float* v            = (float*)(ws + 4096 + 131072);              // 8 KiB
  unsigned short* Cst = (unsigned short*)(ws + 4096 + 131072 + 8192); // 1 MiB

  k_prep<<<40, 256, 0, stream>>>(Wbil, blr, WbT, v);
  k_cpre<<<32, 256, 0, stream>>>(Wlr, WbT, Cst);
  k_fused<<<NB, 512, 0, stream>>>(zsrc, zdst, idx, Cst, v, bbil, out);
}

// Round 9
// 84.501 us; speedup vs baseline: 1.5258x; 1.1709x over previous
//
#include <hip/hip_runtime.h>
#include <hip/hip_bf16.h>
#include <cstddef>

#define NE 65536
#define ND 256
#define NP 8
#define RBLK 64              // routing blocks
#define EPB (NE / RBLK)      // 1024 edges per routing block
#define MAXT 1032            // max tiles: 1024 + 7

typedef short bf16x8 __attribute__((ext_vector_type(8)));
typedef float f32x4  __attribute__((ext_vector_type(4)));

__device__ __forceinline__ unsigned short f2bf(float f) {
  unsigned int u = __float_as_uint(f);
  u += 0x7FFFu + ((u >> 16) & 1u);   // round-to-nearest-even
  return (unsigned short)(u >> 16);
}
__device__ __forceinline__ float bf2f(unsigned short h) {
  return __uint_as_float(((unsigned int)h) << 16);
}

// idx dtype sniff: odd 32-bit words all-zero <=> int64 (values < 8)
__device__ __forceinline__ int sniff_is32(const void* idxraw, int* lflag) {
  int tid = threadIdx.x;
  if (tid == 0) *lflag = 0;
  __syncthreads();
  const unsigned int* w = (const unsigned int*)idxraw;
  unsigned int val = w[((blockIdx.x & 63) * 256 + (tid & 255)) * 2 + 1];
  if (__any(val != 0) && (tid & 63) == 0) atomicOr(lflag, 1);
  __syncthreads();
  return *lflag;
}
__device__ __forceinline__ int load_idx(const void* idxraw, int is32, int e) {
  return is32 ? ((const int*)idxraw)[e] : (int)((const long long*)idxraw)[e];
}

// ---- phase 1: per-block LDS histogram ----
__global__ __launch_bounds__(256) void k_hist(const void* __restrict__ idxraw,
                                              int* __restrict__ counts) {
  __shared__ int h[NP];
  __shared__ int lflag;
  int tid = threadIdx.x;
  int is32 = sniff_is32(idxraw, &lflag);
  if (tid < NP) h[tid] = 0;
  __syncthreads();
  int base = blockIdx.x * EPB;
#pragma unroll
  for (int i = 0; i < EPB / 256; ++i) {
    int p = load_idx(idxraw, is32, base + tid + i * 256);
    atomicAdd(&h[p], 1);
  }
  __syncthreads();
  if (tid < NP) counts[blockIdx.x * NP + tid] = h[tid];
}

// ---- phase 2: totals, CSR offsets, tile prefix, per-block bases ----
__global__ __launch_bounds__(64) void k_scan(const int* __restrict__ counts,
                                             int* __restrict__ hdr,
                                             int* __restrict__ bases) {
  __shared__ int cnt[NP];
  __shared__ int off[NP + 1];
  int q = threadIdx.x;
  if (q < NP) {
    int s = 0;
    for (int b = 0; b < RBLK; ++b) s += counts[b * NP + q];
    cnt[q] = s;
  }
  __syncthreads();
  if (q == 0) {
    int o = 0, tt = 0;
    for (int p = 0; p < NP; ++p) {
      off[p] = o; hdr[p] = o; hdr[9 + p] = tt;
      o += cnt[p];
      tt += (cnt[p] + 63) >> 6;
    }
    off[NP] = o; hdr[NP] = o; hdr[9 + NP] = tt;
  }
  __syncthreads();
  if (q < NP) {
    int run = off[q];
    for (int b = 0; b < RBLK; ++b) {
      bases[b * NP + q] = run;
      run += counts[b * NP + q];
    }
  }
}

// ---- phase 3: CSR scatter with LDS cursors ----
__global__ __launch_bounds__(256) void k_scatter(const void* __restrict__ idxraw,
                                                 const int* __restrict__ bases,
                                                 int* __restrict__ perm) {
  __shared__ int cur[NP];
  __shared__ int lflag;
  int tid = threadIdx.x;
  int is32 = sniff_is32(idxraw, &lflag);
  if (tid < NP) cur[tid] = bases[blockIdx.x * NP + tid];
  __syncthreads();
  int base = blockIdx.x * EPB;
#pragma unroll
  for (int i = 0; i < EPB / 256; ++i) {
    int e = base + tid + i * 256;
    int p = load_idx(idxraw, is32, e);
    int slot = atomicAdd(&cur[p], 1);
    perm[slot] = e;
  }
}

// ---- prep: W_bil -> B-frag bf16 layout; v_p = b_lr[p] @ W_bil (fp32) ----
__global__ __launch_bounds__(256) void k_prep(const float* __restrict__ Wbil,
                                              const float* __restrict__ blr,
                                              unsigned short* __restrict__ WbT,
                                              float* __restrict__ v) {
  int b = blockIdx.x, t = threadIdx.x;
  if (b < 32) {
    int s = b * 256 + t;
    int kt = s >> 10, c = (s >> 6) & 15, l = s & 63;
    int col = c * 16 + (l & 15);
    int k0 = kt * 32 + (l >> 4) * 8;
    union { uint4 u; unsigned short h[8]; } uu;
#pragma unroll
    for (int j = 0; j < 8; ++j)
      uu.h[j] = f2bf(Wbil[(k0 + j) * ND + col]);
    *(uint4*)(WbT + (size_t)s * 8) = uu.u;
  } else {
    int p = b - 32;
    float s = 0.f;
    for (int k = 0; k < ND; ++k)
      s = fmaf(blr[p * ND + k], Wbil[k * ND + t], s);
    v[p * ND + t] = s;
  }
}

// ---- C_p = W_lr[p]^T @ W_bil  (bf16 MFMA), written in B-frag layout ----
__global__ __launch_bounds__(256) void k_cpre(const float* __restrict__ Wlr,
                                              const unsigned short* __restrict__ WbT,
                                              unsigned short* __restrict__ Cst) {
  __shared__ unsigned short aF[2048 * 8];
  int blk = blockIdx.x;
  int p = blk >> 2;
  int i0 = (blk & 3) * 64;
  int tid = threadIdx.x;
  const float* Wp = Wlr + (size_t)p * ND * ND;
#pragma unroll
  for (int it = 0; it < 8; ++it) {
    int s = tid + it * 256;
    int kt = s >> 8, r = (s >> 6) & 3, l = s & 63;
    int i = r * 16 + (l & 15);
    int k0 = kt * 32 + (l >> 4) * 8;
    union { uint4 u; unsigned short h[8]; } uu;
#pragma unroll
    for (int j = 0; j < 8; ++j)
      uu.h[j] = f2bf(Wp[(size_t)(k0 + j) * ND + i0 + i]);
    *(uint4*)(aF + (size_t)s * 8) = uu.u;
  }
  __syncthreads();
  int w = tid >> 6, l = tid & 63;
  f32x4 zero = {0.f, 0.f, 0.f, 0.f};
  f32x4 acc[16];
#pragma unroll
  for (int c = 0; c < 16; ++c) acc[c] = zero;
  for (int kt = 0; kt < 8; ++kt) {
    bf16x8 a = *(const bf16x8*)(aF + (size_t)((kt * 4 + w) * 64 + l) * 8);
#pragma unroll
    for (int c = 0; c < 16; ++c) {
      bf16x8 bb = *(const bf16x8*)(WbT + (size_t)((kt * 16 + c) * 64 + l) * 8);
      acc[c] = __builtin_amdgcn_mfma_f32_16x16x32_bf16(a, bb, acc[c], 0, 0, 0);
    }
  }
  unsigned short* Cp = Cst + (size_t)p * ND * ND;
#pragma unroll
  for (int c = 0; c < 16; ++c) {
#pragma unroll
    for (int q = 0; q < 4; ++q) {
      int i = i0 + w * 16 + ((l >> 4) * 4) + q;
      int j = c * 16 + (l & 15);
      int pos = ((i >> 5) * 16 + (j >> 4)) * 512 + (((i >> 3) & 3) * 16 + (j & 15)) * 8 + (i & 7);
      Cp[pos] = f2bf(acc[c][q]);
    }
  }
}

// ---- main v9: CSR 64-row single-expert tiles, 512 threads (8 waves x 32 cols)
// -> 2 blocks/CU x 8 waves = 16 waves/CU for latency hiding. Straight-line
// fully-unrolled MFMA loop: B frag loaded once per (kt,cl), 4 MFMAs consume it
// immediately; acc[4][2]=32 VGPR keeps the kernel in the <=128-VGPR class.
__global__ __launch_bounds__(512, 4) void k_main(const float* __restrict__ zsrc,
                                                 const float* __restrict__ zdst,
                                                 const int* __restrict__ perm,
                                                 const int* __restrict__ hdr,
                                                 const unsigned short* __restrict__ Cst,
                                                 const float* __restrict__ v,
                                                 const float* __restrict__ bbil,
                                                 float* __restrict__ out) {
  __shared__ unsigned short aF[16384];   // 32 KiB zsrc tile, frag+XOR layout
  __shared__ unsigned short zL[16384];   // 32 KiB zdst tile, row-major+XOR
  __shared__ float red[8][64];           // 2 KiB
  __shared__ int eids[64];
  __shared__ int shdr[18];
  int tid = threadIdx.x;
  if (tid < 18) shdr[tid] = hdr[tid];
  __syncthreads();
  int bid = blockIdx.x;
  if (bid >= shdr[9 + NP]) return;
  int p = 0;
  while (p < NP - 1 && bid >= shdr[9 + p + 1]) ++p;
  int t = bid - shdr[9 + p];
  int cnt = shdr[p + 1] - shdr[p];
  int ebase = shdr[p] + t * 64;
  int nrow = cnt - t * 64; if (nrow > 64) nrow = 64;
  if (tid < 64) eids[tid] = perm[ebase + (tid < nrow ? tid : nrow - 1)];
  __syncthreads();
  int w = tid >> 6, l = tid & 63;

  // ---- staging: wave w owns rows [w*8, w*8+8); lane l cols [4l, 4l+4) ----
  int kt0 = l >> 3, pos0 = (l & 7) >> 1, par0 = l & 1;
#pragma unroll
  for (int i = 0; i < 8; ++i) {
    int row = w * 8 + i;
    int e = eids[row];
    float4 fs = *(const float4*)(zsrc + (size_t)e * ND + l * 4);
    float4 fd = *(const float4*)(zdst + (size_t)e * ND + l * 4);
    union { ushort4 u; unsigned short hh[4]; } us, ud;
    us.hh[0] = f2bf(fs.x); us.hh[1] = f2bf(fs.y); us.hh[2] = f2bf(fs.z); us.hh[3] = f2bf(fs.w);
    ud.hh[0] = f2bf(fd.x); ud.hh[1] = f2bf(fd.y); ud.hh[2] = f2bf(fd.z); ud.hh[3] = f2bf(fd.w);
    *(ushort4*)((char*)zL + row * 512 + ((l * 8) ^ ((row & 7) << 4))) = ud.u;
    unsigned byte = (unsigned)(((kt0 * 4 + (row >> 4)) << 10) | (pos0 << 8) | ((row & 15) << 4) | (par0 << 3));
    byte ^= (unsigned)(((kt0 & 3) << 5) ^ ((pos0 & 1) << 4));
    *(ushort4*)((char*)aF + byte) = us.u;
  }
  __syncthreads();

  // ---- GEMM: wave w covers col-tiles {2w, 2w+1}; rows all 4 strips ----
  const unsigned short* Cp = Cst + (size_t)p * ND * ND;
  f32x4 zero = {0.f, 0.f, 0.f, 0.f};
  f32x4 acc[4][2];
#pragma unroll
  for (int sr = 0; sr < 4; ++sr)
#pragma unroll
    for (int cl = 0; cl < 2; ++cl) acc[sr][cl] = zero;
  int pos = l >> 4;
#pragma unroll
  for (int kt = 0; kt < 8; ++kt) {
    bf16x8 a[4];
#pragma unroll
    for (int sr = 0; sr < 4; ++sr) {
      unsigned byte = (unsigned)(((kt * 4 + sr) << 10) | (pos << 8) | ((l & 15) << 4));
      byte ^= (unsigned)(((kt & 3) << 5) ^ ((pos & 1) << 4));
      a[sr] = *(const bf16x8*)((const char*)aF + byte);
    }
#pragma unroll
    for (int cl = 0; cl < 2; ++cl) {
      bf16x8 bb = *(const bf16x8*)(Cp + (size_t)((kt * 16 + (w * 2 + cl)) * 64 + l) * 8);
#pragma unroll
      for (int sr = 0; sr < 4; ++sr)
        acc[sr][cl] = __builtin_amdgcn_mfma_f32_16x16x32_bf16(a[sr], bb, acc[sr][cl], 0, 0, 0);
    }
  }

  // ---- fused epilogue: score_row += sum_col (t+v)*zdst over this wave's 32 cols
  float vloc[2];
#pragma unroll
  for (int cl = 0; cl < 2; ++cl)
    vloc[cl] = v[p * ND + (w * 2 + cl) * 16 + (l & 15)];
#pragma unroll
  for (int sr = 0; sr < 4; ++sr) {
#pragma unroll
    for (int q = 0; q < 4; ++q) {
      int row = sr * 16 + (l >> 4) * 4 + q;    // D-layout: col=l&15, row=(l>>4)*4+reg
      unsigned swz = (unsigned)((row & 7) << 4);
      float sv = 0.f;
#pragma unroll
      for (int cl = 0; cl < 2; ++cl) {
        int col = (w * 2 + cl) * 16 + (l & 15);
        unsigned zb = (unsigned)(row * 512) + (((unsigned)(col * 2)) ^ swz);
        sv = fmaf(acc[sr][cl][q] + vloc[cl], bf2f(*(const unsigned short*)((const char*)zL + zb)), sv);
      }
      sv += __shfl_xor(sv, 1, 64);
      sv += __shfl_xor(sv, 2, 64);
      sv += __shfl_xor(sv, 4, 64);
      sv += __shfl_xor(sv, 8, 64);
      if ((l & 15) == 0) red[w][row] = sv;
    }
  }
  __syncthreads();
  if (tid < 64 && tid < nrow) {
    float sc = bbil[0];
#pragma unroll
    for (int ww = 0; ww < 8; ++ww) sc += red[ww][tid];
    out[eids[tid]] = sc;
  }
}

extern "C" void kernel_launch(void* const* d_in, const int* in_sizes, int n_in,
                              void* d_out, int out_size, void* d_ws, size_t ws_size,
                              hipStream_t stream) {
  // setup_inputs() dict order: z_src, z_dst, W_lr, b_lr, W_bil, b_bil, lr_pair_idx
  const float* zsrc = (const float*)d_in[0];
  const float* zdst = (const float*)d_in[1];
  const float* Wlr  = (const float*)d_in[2];
  const float* blr  = (const float*)d_in[3];
  const float* Wbil = (const float*)d_in[4];
  const float* bbil = (const float*)d_in[5];
  const void*  idx  = (const void*)d_in[6];
  float* out = (float*)d_out;

  char* ws = (char*)d_ws;
  int* hdr    = (int*)ws;                                  // 72 B
  int* counts = (int*)(ws + 4096);                         // 2 KiB
  int* bases  = (int*)(ws + 8192);                         // 2 KiB
  int* perm   = (int*)(ws + 16384);                        // 256 KiB (CSR)
  unsigned short* WbT = (unsigned short*)(ws + 16384 + (size_t)NE * 4);            // 128 KiB
  float* v = (float*)(ws + 16384 + (size_t)NE * 4 + 131072);                       // 8 KiB
  unsigned short* Cst = (unsigned short*)(ws + 16384 + (size_t)NE * 4 + 131072 + 8192); // 1 MiB

  k_prep<<<40, 256, 0, stream>>>(Wbil, blr, WbT, v);
  k_hist<<<RBLK, 256, 0, stream>>>(idx, counts);
  k_scan<<<1, 64, 0, stream>>>(counts, hdr, bases);
  k_scatter<<<RBLK, 256, 0, stream>>>(idx, bases, perm);
  k_cpre<<<32, 256, 0, stream>>>(Wlr, WbT, Cst);
  k_main<<<MAXT, 512, 0, stream>>>(zsrc, zdst, perm, hdr, Cst, v, bbil, out);
}